// Round 1
// baseline (431.998 us; speedup 1.0000x reference)
//
#include <hip/hip_runtime.h>

#define NGRAPH 256
#define FIN 64
#define HID 32

// K1: per-node 64->32 double matmul.  A = x @ Wrel, B = x @ Wroot + bias
__global__ __launch_bounds__(256) void node_lin64(
    const float* __restrict__ x, const float* __restrict__ Wrel,
    const float* __restrict__ Wroot, const float* __restrict__ bias,
    float* __restrict__ A, float* __restrict__ B, int N)
{
    __shared__ float sWr[FIN * HID];
    __shared__ float sWo[FIN * HID];
    __shared__ float sb[HID];
    __shared__ float sx[8 * FIN];
    int tid = threadIdx.x;
    for (int i = tid; i < FIN * HID; i += 256) { sWr[i] = Wrel[i]; sWo[i] = Wroot[i]; }
    if (tid < HID) sb[tid] = bias[tid];
    int base = blockIdx.x * 8;
    for (int i = tid; i < 8 * FIN; i += 256) {
        int n = base + i / FIN;
        sx[i] = (n < N) ? x[(size_t)n * FIN + (i % FIN)] : 0.f;
    }
    __syncthreads();
    int nl = tid >> 5;      // node within tile: 0..7
    int f  = tid & 31;      // output feature
    int n  = base + nl;
    if (n >= N) return;
    float ar = 0.f, ao = 0.f;
    #pragma unroll
    for (int k = 0; k < FIN; ++k) {
        float xv = sx[nl * FIN + k];
        ar = fmaf(xv, sWr[k * HID + f], ar);
        ao = fmaf(xv, sWo[k * HID + f], ao);
    }
    A[(size_t)n * HID + f] = ar;
    B[(size_t)n * HID + f] = ao + sb[f];
}

// K3: per-node relu + 32->32 double matmul.  h=relu(Hpre); A=h@Wrel, C=h@Wroot+bias
__global__ __launch_bounds__(256) void node_lin32(
    const float* __restrict__ Hpre, const float* __restrict__ Wrel,
    const float* __restrict__ Wroot, const float* __restrict__ bias,
    float* __restrict__ A, float* __restrict__ C, int N)
{
    __shared__ float sWr[HID * HID];
    __shared__ float sWo[HID * HID];
    __shared__ float sb[HID];
    __shared__ float sh[8 * HID];
    int tid = threadIdx.x;
    for (int i = tid; i < HID * HID; i += 256) { sWr[i] = Wrel[i]; sWo[i] = Wroot[i]; }
    if (tid < HID) sb[tid] = bias[tid];
    int base = blockIdx.x * 8;
    for (int i = tid; i < 8 * HID; i += 256) {
        int n = base + i / HID;
        float v = (n < N) ? Hpre[(size_t)n * HID + (i % HID)] : 0.f;
        sh[i] = v > 0.f ? v : 0.f;
    }
    __syncthreads();
    int nl = tid >> 5, f = tid & 31, n = base + nl;
    if (n >= N) return;
    float ar = 0.f, ao = 0.f;
    #pragma unroll
    for (int k = 0; k < HID; ++k) {
        float hv = sh[nl * HID + k];
        ar = fmaf(hv, sWr[k * HID + f], ar);
        ao = fmaf(hv, sWo[k * HID + f], ao);
    }
    A[(size_t)n * HID + f] = ar;
    C[(size_t)n * HID + f] = ao + sb[f];
}

// K2/K4: edge scatter.  out[dst] += A[src] * ew   (one thread per edge-feature)
__global__ __launch_bounds__(256) void scatter_add(
    const int* __restrict__ src, const int* __restrict__ dst,
    const float* __restrict__ ew, const float* __restrict__ A,
    float* __restrict__ out, int E)
{
    int gid = blockIdx.x * 256 + threadIdx.x;
    int e = gid >> 5, f = gid & 31;
    if (e >= E) return;
    int s = src[e], d = dst[e];
    float w = ew[e];
    atomicAdd(&out[(size_t)d * HID + f], A[(size_t)s * HID + f] * w);
}

// K5: relu + segment-sum pool over sorted batch ids (running-sum, flush on change)
__global__ __launch_bounds__(256) void pool_kernel(
    const float* __restrict__ C, const int* __restrict__ batch,
    float* __restrict__ sums, float* __restrict__ cnts, int N)
{
    int f = threadIdx.x & 31, g = threadIdx.x >> 5;
    int n0 = blockIdx.x * 256 + g * 32;
    if (n0 >= N) return;
    int n1 = n0 + 32; if (n1 > N) n1 = N;
    int cur = batch[n0];
    float acc = 0.f, cnt = 0.f;
    for (int n = n0; n < n1; ++n) {
        int b = batch[n];
        if (b != cur) {
            atomicAdd(&sums[cur * HID + f], acc);
            if (f == 0) atomicAdd(&cnts[cur], cnt);
            acc = 0.f; cnt = 0.f; cur = b;
        }
        float v = C[(size_t)n * HID + f];
        acc += v > 0.f ? v : 0.f;
        cnt += 1.f;
    }
    atomicAdd(&sums[cur * HID + f], acc);
    if (f == 0) atomicAdd(&cnts[cur], cnt);
}

// K6: final MLP over 256 graphs, one thread per graph
__global__ __launch_bounds__(256) void mlp_kernel(
    const float* __restrict__ sums, const float* __restrict__ cnts,
    const float* __restrict__ W1, const float* __restrict__ b1,
    const float* __restrict__ W2, const float* __restrict__ b2,
    const float* __restrict__ W3, const float* __restrict__ b3,
    float* __restrict__ out)
{
    __shared__ float sW1[32 * 32], sb1[32], sW2[32 * 16], sb2[16], sW3[16], sb3;
    int tid = threadIdx.x;
    for (int i = tid; i < 32 * 32; i += 256) sW1[i] = W1[i];
    for (int i = tid; i < 32 * 16; i += 256) sW2[i] = W2[i];
    if (tid < 32) sb1[tid] = b1[tid];
    if (tid < 16) { sb2[tid] = b2[tid]; sW3[tid] = W3[tid]; }
    if (tid == 0) sb3 = b3[0];
    __syncthreads();
    int gi = tid;  // 256 graphs, 256 threads
    float c = cnts[gi]; c = c > 1.f ? c : 1.f;
    float inv = 1.f / c;
    float gvec[32];
    #pragma unroll
    for (int i = 0; i < 32; ++i) gvec[i] = sums[gi * 32 + i] * inv;
    float h1[32];
    #pragma unroll
    for (int j = 0; j < 32; ++j) {
        float a = sb1[j];
        #pragma unroll
        for (int k = 0; k < 32; ++k) a = fmaf(gvec[k], sW1[k * 32 + j], a);
        h1[j] = a > 0.f ? a : 0.f;
    }
    float o = sb3;
    #pragma unroll
    for (int j = 0; j < 16; ++j) {
        float a = sb2[j];
        #pragma unroll
        for (int k = 0; k < 32; ++k) a = fmaf(h1[k], sW2[k * 16 + j], a);
        a = a > 0.f ? a : 0.f;       // relu after lin2
        o = fmaf(a, sW3[j], o);
    }
    out[gi] = o;
}

extern "C" void kernel_launch(void* const* d_in, const int* in_sizes, int n_in,
                              void* d_out, int out_size, void* d_ws, size_t ws_size,
                              hipStream_t stream) {
    const float* x     = (const float*)d_in[0];
    const int*   ei    = (const int*)d_in[1];
    const float* ew    = (const float*)d_in[2];
    const int*   batch = (const int*)d_in[3];
    const float* c1rw  = (const float*)d_in[4];
    const float* c1rb  = (const float*)d_in[5];
    const float* c1ow  = (const float*)d_in[6];
    const float* c2rw  = (const float*)d_in[7];
    const float* c2rb  = (const float*)d_in[8];
    const float* c2ow  = (const float*)d_in[9];
    const float* l1w   = (const float*)d_in[10];
    const float* l1b   = (const float*)d_in[11];
    const float* l2w   = (const float*)d_in[12];
    const float* l2b   = (const float*)d_in[13];
    const float* lw    = (const float*)d_in[14];
    const float* lb    = (const float*)d_in[15];

    int N = in_sizes[0] / FIN;      // 100000
    int E = in_sizes[2];            // 1600000
    const int* src = ei;
    const int* dst = ei + E;

    float* A    = (float*)d_ws;                    // [N,32] rel-projected features
    float* B    = A + (size_t)N * HID;             // [N,32] conv1 accumulator
    float* C    = B + (size_t)N * HID;             // [N,32] conv2 accumulator
    float* sums = C + (size_t)N * HID;             // [256,32]
    float* cnts = sums + NGRAPH * HID;             // [256]

    hipMemsetAsync(sums, 0, (NGRAPH * HID + NGRAPH) * sizeof(float), stream);

    int nb_node = (N + 7) / 8;
    int nb_edge = (int)(((long long)E * 32 + 255) / 256);

    node_lin64<<<nb_node, 256, 0, stream>>>(x, c1rw, c1ow, c1rb, A, B, N);
    scatter_add<<<nb_edge, 256, 0, stream>>>(src, dst, ew, A, B, E);
    node_lin32<<<nb_node, 256, 0, stream>>>(B, c2rw, c2ow, c2rb, A, C, N);
    scatter_add<<<nb_edge, 256, 0, stream>>>(src, dst, ew, A, C, E);
    pool_kernel<<<(N + 255) / 256, 256, 0, stream>>>(C, batch, sums, cnts, N);
    mlp_kernel<<<1, 256, 0, stream>>>(sums, cnts, l1w, l1b, l2w, l2b, lw, lb,
                                      (float*)d_out);
}

// Round 2
// 385.724 us; speedup vs baseline: 1.1200x; 1.1200x over previous
//
#include <hip/hip_runtime.h>

#define NGRAPH 256
#define FIN 64
#define HID 32

// ---------- node GEMMs ----------
__global__ __launch_bounds__(256) void node_lin64(
    const float* __restrict__ x, const float* __restrict__ Wrel,
    const float* __restrict__ Wroot, const float* __restrict__ bias,
    float* __restrict__ A, float* __restrict__ B, int N)
{
    __shared__ float sWr[FIN * HID];
    __shared__ float sWo[FIN * HID];
    __shared__ float sb[HID];
    __shared__ float sx[8 * FIN];
    int tid = threadIdx.x;
    for (int i = tid; i < FIN * HID; i += 256) { sWr[i] = Wrel[i]; sWo[i] = Wroot[i]; }
    if (tid < HID) sb[tid] = bias[tid];
    int base = blockIdx.x * 8;
    for (int i = tid; i < 8 * FIN; i += 256) {
        int n = base + i / FIN;
        sx[i] = (n < N) ? x[(size_t)n * FIN + (i % FIN)] : 0.f;
    }
    __syncthreads();
    int nl = tid >> 5, f = tid & 31, n = base + nl;
    if (n >= N) return;
    float ar = 0.f, ao = 0.f;
    #pragma unroll
    for (int k = 0; k < FIN; ++k) {
        float xv = sx[nl * FIN + k];
        ar = fmaf(xv, sWr[k * HID + f], ar);
        ao = fmaf(xv, sWo[k * HID + f], ao);
    }
    A[(size_t)n * HID + f] = ar;
    B[(size_t)n * HID + f] = ao + sb[f];
}

__global__ __launch_bounds__(256) void node_lin32(
    const float* __restrict__ Hpre, const float* __restrict__ Wrel,
    const float* __restrict__ Wroot, const float* __restrict__ bias,
    float* __restrict__ A, float* __restrict__ C, int N)
{
    __shared__ float sWr[HID * HID];
    __shared__ float sWo[HID * HID];
    __shared__ float sb[HID];
    __shared__ float sh[8 * HID];
    int tid = threadIdx.x;
    for (int i = tid; i < HID * HID; i += 256) { sWr[i] = Wrel[i]; sWo[i] = Wroot[i]; }
    if (tid < HID) sb[tid] = bias[tid];
    int base = blockIdx.x * 8;
    for (int i = tid; i < 8 * HID; i += 256) {
        int n = base + i / HID;
        float v = (n < N) ? Hpre[(size_t)n * HID + (i % HID)] : 0.f;
        sh[i] = v > 0.f ? v : 0.f;
    }
    __syncthreads();
    int nl = tid >> 5, f = tid & 31, n = base + nl;
    if (n >= N) return;
    float ar = 0.f, ao = 0.f;
    #pragma unroll
    for (int k = 0; k < HID; ++k) {
        float hv = sh[nl * HID + k];
        ar = fmaf(hv, sWr[k * HID + f], ar);
        ao = fmaf(hv, sWo[k * HID + f], ao);
    }
    A[(size_t)n * HID + f] = ar;
    C[(size_t)n * HID + f] = ao + sb[f];
}

// ---------- CSR build ----------
__global__ __launch_bounds__(256) void hist_kernel(
    const int* __restrict__ dst, int* __restrict__ cnt, int E)
{
    int e = blockIdx.x * 256 + threadIdx.x;
    if (e < E) atomicAdd(&cnt[dst[e]], 1);
}

// per-block (1024 elements) inclusive scan -> rowptr[1+i], block totals
__global__ __launch_bounds__(256) void scanA(
    const int* __restrict__ cnt, int* __restrict__ rowptr1 /* = rowptr+1 */,
    int* __restrict__ blockSums, int N)
{
    __shared__ int lds[256];
    int t = threadIdx.x;
    int base = blockIdx.x * 1024 + t * 4;
    int v0 = (base + 0 < N) ? cnt[base + 0] : 0;
    int v1 = (base + 1 < N) ? cnt[base + 1] : 0;
    int v2 = (base + 2 < N) ? cnt[base + 2] : 0;
    int v3 = (base + 3 < N) ? cnt[base + 3] : 0;
    int s = v0 + v1 + v2 + v3;
    lds[t] = s;
    __syncthreads();
    int acc = s;
    for (int off = 1; off < 256; off <<= 1) {
        int add = (t >= off) ? lds[t - off] : 0;
        __syncthreads();
        acc += add;
        lds[t] = acc;
        __syncthreads();
    }
    int run = acc - s;  // exclusive prefix of this thread
    run += v0; if (base + 0 < N) rowptr1[base + 0] = run;
    run += v1; if (base + 1 < N) rowptr1[base + 1] = run;
    run += v2; if (base + 2 < N) rowptr1[base + 2] = run;
    run += v3; if (base + 3 < N) rowptr1[base + 3] = run;
    if (t == 255) blockSums[blockIdx.x] = acc;
}

__global__ void scanB(const int* __restrict__ blockSums,
                      int* __restrict__ blockOff, int* __restrict__ rowptr, int nb)
{
    if (threadIdx.x == 0 && blockIdx.x == 0) {
        int run = 0;
        for (int b = 0; b < nb; ++b) { blockOff[b] = run; run += blockSums[b]; }
        rowptr[0] = 0;
    }
}

__global__ __launch_bounds__(256) void scanC(
    int* __restrict__ rowptr1, const int* __restrict__ blockOff, int N)
{
    int b = blockIdx.x;
    int off = blockOff[b];
    int base = b * 1024 + threadIdx.x * 4;
    #pragma unroll
    for (int k = 0; k < 4; ++k)
        if (base + k < N) rowptr1[base + k] += off;
}

__global__ __launch_bounds__(256) void fill_kernel(
    const int* __restrict__ src, const int* __restrict__ dst,
    const float* __restrict__ ew, const int* __restrict__ rowptr,
    int* __restrict__ cursor, int2* __restrict__ perm, int E)
{
    int e = blockIdx.x * 256 + threadIdx.x;
    if (e >= E) return;
    int d = dst[e];
    int pos = rowptr[d] + atomicAdd(&cursor[d], 1);
    perm[pos] = make_int2(src[e], __float_as_int(ew[e]));
}

// ---------- gather-side aggregation: out[n] += sum_e w_e * A[src_e] ----------
__global__ __launch_bounds__(256) void csr_agg(
    const int* __restrict__ rowptr, const int2* __restrict__ perm,
    const float* __restrict__ A, float* __restrict__ out, int N)
{
    int gid = blockIdx.x * 256 + threadIdx.x;
    int n = gid >> 5, f = gid & 31;
    if (n >= N) return;
    int e0 = rowptr[n], e1 = rowptr[n + 1];
    float acc0 = 0.f, acc1 = 0.f;
    int e = e0;
    for (; e + 1 < e1; e += 2) {
        int2 p0 = perm[e];
        int2 p1 = perm[e + 1];
        acc0 = fmaf(A[(size_t)p0.x * HID + f], __int_as_float(p0.y), acc0);
        acc1 = fmaf(A[(size_t)p1.x * HID + f], __int_as_float(p1.y), acc1);
    }
    if (e < e1) {
        int2 p = perm[e];
        acc0 = fmaf(A[(size_t)p.x * HID + f], __int_as_float(p.y), acc0);
    }
    out[(size_t)n * HID + f] += acc0 + acc1;
}

// ---------- pool + MLP ----------
__global__ __launch_bounds__(256) void pool_kernel(
    const float* __restrict__ C, const int* __restrict__ batch,
    float* __restrict__ sums, float* __restrict__ cnts, int N)
{
    int f = threadIdx.x & 31, g = threadIdx.x >> 5;
    int n0 = blockIdx.x * 256 + g * 32;
    if (n0 >= N) return;
    int n1 = n0 + 32; if (n1 > N) n1 = N;
    int cur = batch[n0];
    float acc = 0.f, cnt = 0.f;
    for (int n = n0; n < n1; ++n) {
        int b = batch[n];
        if (b != cur) {
            atomicAdd(&sums[cur * HID + f], acc);
            if (f == 0) atomicAdd(&cnts[cur], cnt);
            acc = 0.f; cnt = 0.f; cur = b;
        }
        float v = C[(size_t)n * HID + f];
        acc += v > 0.f ? v : 0.f;
        cnt += 1.f;
    }
    atomicAdd(&sums[cur * HID + f], acc);
    if (f == 0) atomicAdd(&cnts[cur], cnt);
}

__global__ __launch_bounds__(256) void mlp_kernel(
    const float* __restrict__ sums, const float* __restrict__ cnts,
    const float* __restrict__ W1, const float* __restrict__ b1,
    const float* __restrict__ W2, const float* __restrict__ b2,
    const float* __restrict__ W3, const float* __restrict__ b3,
    float* __restrict__ out)
{
    __shared__ float sW1[32 * 32], sb1[32], sW2[32 * 16], sb2[16], sW3[16], sb3;
    int tid = threadIdx.x;
    for (int i = tid; i < 32 * 32; i += 256) sW1[i] = W1[i];
    for (int i = tid; i < 32 * 16; i += 256) sW2[i] = W2[i];
    if (tid < 32) sb1[tid] = b1[tid];
    if (tid < 16) { sb2[tid] = b2[tid]; sW3[tid] = W3[tid]; }
    if (tid == 0) sb3 = b3[0];
    __syncthreads();
    int gi = tid;
    float c = cnts[gi]; c = c > 1.f ? c : 1.f;
    float inv = 1.f / c;
    float gvec[32];
    #pragma unroll
    for (int i = 0; i < 32; ++i) gvec[i] = sums[gi * 32 + i] * inv;
    float h1[32];
    #pragma unroll
    for (int j = 0; j < 32; ++j) {
        float a = sb1[j];
        #pragma unroll
        for (int k = 0; k < 32; ++k) a = fmaf(gvec[k], sW1[k * 32 + j], a);
        h1[j] = a > 0.f ? a : 0.f;
    }
    float o = sb3;
    #pragma unroll
    for (int j = 0; j < 16; ++j) {
        float a = sb2[j];
        #pragma unroll
        for (int k = 0; k < 32; ++k) a = fmaf(h1[k], sW2[k * 16 + j], a);
        a = a > 0.f ? a : 0.f;
        o = fmaf(a, sW3[j], o);
    }
    out[gi] = o;
}

extern "C" void kernel_launch(void* const* d_in, const int* in_sizes, int n_in,
                              void* d_out, int out_size, void* d_ws, size_t ws_size,
                              hipStream_t stream) {
    const float* x     = (const float*)d_in[0];
    const int*   ei    = (const int*)d_in[1];
    const float* ew    = (const float*)d_in[2];
    const int*   batch = (const int*)d_in[3];
    const float* c1rw  = (const float*)d_in[4];
    const float* c1rb  = (const float*)d_in[5];
    const float* c1ow  = (const float*)d_in[6];
    const float* c2rw  = (const float*)d_in[7];
    const float* c2rb  = (const float*)d_in[8];
    const float* c2ow  = (const float*)d_in[9];
    const float* l1w   = (const float*)d_in[10];
    const float* l1b   = (const float*)d_in[11];
    const float* l2w   = (const float*)d_in[12];
    const float* l2b   = (const float*)d_in[13];
    const float* lw    = (const float*)d_in[14];
    const float* lb    = (const float*)d_in[15];

    int N = in_sizes[0] / FIN;      // 100000
    int E = in_sizes[2];            // 1600000
    const int* src = ei;
    const int* dst = ei + E;

    // ---- workspace layout (4B units) ----
    char* ws = (char*)d_ws;
    size_t off = 0;
    auto alloc = [&](size_t nbytes) { void* p = ws + off; off += (nbytes + 15) & ~size_t(15); return p; };
    float* A       = (float*)alloc((size_t)N * HID * 4);
    float* B       = (float*)alloc((size_t)N * HID * 4);
    float* C       = (float*)alloc((size_t)N * HID * 4);
    int*   cnt     = (int*)  alloc((size_t)N * 4);
    int*   rowptr  = (int*)  alloc((size_t)(N + 1) * 4);
    int*   cursor  = (int*)  alloc((size_t)N * 4);
    int*   bSums   = (int*)  alloc(256 * 4);
    int*   bOff    = (int*)  alloc(256 * 4);
    int2*  perm    = (int2*) alloc((size_t)E * 8);
    float* sums    = (float*)alloc(NGRAPH * HID * 4);
    float* cnts    = (float*)alloc(NGRAPH * 4);

    hipMemsetAsync(cnt, 0, (size_t)N * 4, stream);
    hipMemsetAsync(cursor, 0, (size_t)N * 4, stream);
    hipMemsetAsync(sums, 0, (NGRAPH * HID + NGRAPH) * 4, stream);

    int nb_edge1 = (E + 255) / 256;
    int nb_scan  = (N + 1023) / 1024;
    int nb_node  = (N + 7) / 8;
    int nb_agg   = (N * HID + 255) / 256;

    // CSR build
    hist_kernel<<<nb_edge1, 256, 0, stream>>>(dst, cnt, E);
    scanA<<<nb_scan, 256, 0, stream>>>(cnt, rowptr + 1, bSums, N);
    scanB<<<1, 64, 0, stream>>>(bSums, bOff, rowptr, nb_scan);
    scanC<<<nb_scan, 256, 0, stream>>>(rowptr + 1, bOff, N);
    fill_kernel<<<nb_edge1, 256, 0, stream>>>(src, dst, ew, rowptr, cursor, perm, E);

    // conv1
    node_lin64<<<nb_node, 256, 0, stream>>>(x, c1rw, c1ow, c1rb, A, B, N);
    csr_agg<<<nb_agg, 256, 0, stream>>>(rowptr, perm, A, B, N);
    // conv2 (relu fused into node_lin32 load)
    node_lin32<<<nb_node, 256, 0, stream>>>(B, c2rw, c2ow, c2rb, A, C, N);
    csr_agg<<<nb_agg, 256, 0, stream>>>(rowptr, perm, A, C, N);
    // pool + MLP
    pool_kernel<<<(N + 255) / 256, 256, 0, stream>>>(C, batch, sums, cnts, N);
    mlp_kernel<<<1, 256, 0, stream>>>(sums, cnts, l1w, l1b, l2w, l2b, lw, lb,
                                      (float*)d_out);
}